// Round 10
// baseline (352.163 us; speedup 1.0000x reference)
//
#include <hip/hip_runtime.h>
#include <hip/hip_bf16.h>
#include <math.h>

#define D_MODEL 768
#define NH 12
#define DFF 3072
#define BB 2
#define SS 2048
#define MM (BB*SS)   /* 4096 rows total */
#define DK 64

typedef _Float16 half8 __attribute__((ext_vector_type(8)));
typedef _Float16 half4 __attribute__((ext_vector_type(4)));
typedef float f32x4 __attribute__((ext_vector_type(4)));

// ---------------------------------------------------------------------------
// fp16 MFMA GEMM, 2-PHASE PIPELINED: C[M,N] = A[M,K] @ W[K,N] + bias.
// A fp16 row-major, W TRANSPOSED fp16 (Bt[N][K]).  Tiles: BM x 128, BK=64.
// 4 waves (2x2), wave tile (AM*16) x 64, mfma_f32_16x16x32_f16.
// Double-buffered LDS; next K-tile's global_load_lds issued BEFORE computing
// the current tile (T3 minimum-2-phase): one vmcnt(0)+barrier per K-step.
// Staging: linear LDS dest + inverse-XOR-swizzled global source; reads use
// the same swizzle (byte ^= (row&7)<<4 on 128B rows)  -> conflict-free.
// EPI: 0 = bias, fp32 C | 1 = bias+GELU, fp16 C | 2 = bias, QKV scatter fp16
// ---------------------------------------------------------------------------
template<int AM, int EPI>
__launch_bounds__(256)
__global__ void hgemm_k(const _Float16* __restrict__ A,
                        const _Float16* __restrict__ Bt,
                        const float* __restrict__ bias,
                        float* __restrict__ Cf, _Float16* __restrict__ Ch,
                        int M, int N, int K,
                        _Float16* __restrict__ qo, _Float16* __restrict__ ko,
                        _Float16* __restrict__ vo)
{
    constexpr int BM = AM * 32;        // 128 or 64
    constexpr int NA = BM / 8;         // A-stage instructions (1024B each)
    constexpr int NI = NA + 16;        // total stage instrs per K-step
    __shared__ _Float16 Als[2][BM * 64];   // [buf][BM][64] fp16, swizzled
    __shared__ _Float16 Bls[2][128 * 64];  // [buf][128][64]

    const int tid  = threadIdx.x;
    const int wv   = tid >> 6, lane = tid & 63;
    const int l15  = lane & 15, lg = lane >> 4;
    const int wr   = wv >> 1,  wc = wv & 1;
    const int m0   = blockIdx.y * BM, n0 = blockIdx.x * 128;

    f32x4 acc[AM][4];
    #pragma unroll
    for (int m = 0; m < AM; m++)
        #pragma unroll
        for (int n = 0; n < 4; n++)
            acc[m][n][0] = acc[m][n][1] = acc[m][n][2] = acc[m][n][3] = 0.0f;

    const char* Ab = (const char*)A;
    const char* Bb = (const char*)Bt;

    // stage K-tile kt into buffer buf: linear dest, inverse-swizzled source
#define GSTAGE(buf, kt)                                                       \
    {                                                                         \
        _Pragma("unroll")                                                     \
        for (int inst = wv; inst < NI; inst += 4) {                           \
            const bool isA = inst < NA;                                       \
            const int  li  = isA ? inst : inst - NA;                          \
            const int  p   = li * 1024 + lane * 16;                           \
            const int  lo  = p ^ (((p >> 7) & 7) << 4);                       \
            const int  row = lo >> 7, kb = lo & 127;                          \
            const char* src = isA                                             \
                ? Ab + ((size_t)(m0 + row) * K + (kt)) * 2 + kb               \
                : Bb + ((size_t)(n0 + row) * K + (kt)) * 2 + kb;              \
            char* dst = (isA ? (char*)Als[buf] : (char*)Bls[buf]) + li * 1024;\
            __builtin_amdgcn_global_load_lds(                                 \
                (const __attribute__((address_space(1))) void*)src,           \
                (__attribute__((address_space(3))) void*)dst, 16, 0, 0);      \
        }                                                                     \
    }

    GSTAGE(0, 0);
    asm volatile("s_waitcnt vmcnt(0)" ::: "memory");
    __syncthreads();

    const int nt = K >> 6;
    for (int it = 0; it < nt; ++it) {
        const int cur = it & 1;
        if (it + 1 < nt) GSTAGE(cur ^ 1, (it + 1) << 6);

        const char* Al = (const char*)Als[cur];
        const char* Bl = (const char*)Bls[cur];

        __builtin_amdgcn_s_setprio(1);
        #pragma unroll
        for (int ks = 0; ks < 2; ks++) {
            half8 af[AM], bf[4];
            #pragma unroll
            for (int m = 0; m < AM; m++) {
                int row = wr * (AM * 16) + m * 16 + l15;
                int off = (row * 128 + ks * 64 + lg * 16) ^ ((row & 7) << 4);
                af[m] = *(const half8*)(Al + off);
            }
            #pragma unroll
            for (int n = 0; n < 4; n++) {
                int row = wc * 64 + n * 16 + l15;
                int off = (row * 128 + ks * 64 + lg * 16) ^ ((row & 7) << 4);
                bf[n] = *(const half8*)(Bl + off);
            }
            #pragma unroll
            for (int m = 0; m < AM; m++)
                #pragma unroll
                for (int n = 0; n < 4; n++)
                    acc[m][n] = __builtin_amdgcn_mfma_f32_16x16x32_f16(
                        af[m], bf[n], acc[m][n], 0, 0, 0);
        }
        __builtin_amdgcn_s_setprio(0);

        // next tile's loads have flown under the compute; drain + flip
        asm volatile("s_waitcnt vmcnt(0)" ::: "memory");
        __syncthreads();
    }
#undef GSTAGE

    // ---- epilogue.  C/D: col=l15, row=lg*4+r
    #pragma unroll
    for (int m = 0; m < AM; m++) {
        #pragma unroll
        for (int n = 0; n < 4; n++) {
            int col = n0 + wc * 64 + n * 16 + l15;
            float bs = bias[col];
            #pragma unroll
            for (int r = 0; r < 4; r++) {
                int row = m0 + wr * (AM * 16) + m * 16 + lg * 4 + r;
                float val = acc[m][n][r] + bs;
                if (EPI == 0) {
                    Cf[(size_t)row * N + col] = val;
                } else if (EPI == 1) {
                    val = 0.5f * val * (1.0f + erff(val * 0.70710678118654752f));
                    Ch[(size_t)row * N + col] = (_Float16)val;
                } else {
                    int which = col / D_MODEL;
                    int c = col - which * D_MODEL;
                    int hh = c >> 6, dd = c & 63;
                    int bq = row >> 11, si = row & 2047;
                    _Float16 hv = (_Float16)val;
                    if (which == 0)
                        qo[((((size_t)bq * NH + hh) * SS) + si) * DK + dd] = hv;
                    else if (which == 1)
                        ko[((((size_t)bq * NH + hh) * SS) + si) * DK + dd] = hv;
                    else
                        vo[(((size_t)bq * NH + hh) * DK + dd) * SS + si] = hv;
                }
            }
        }
    }
}

// ---------------------------------------------------------------------------
// MFMA flash attention v2.1: fp16 in / fp32 accum, log2-domain softmax.
// Block = 4 waves; wave owns 16 q-rows; block covers 64 q-rows of one (b,h).
// K and V^T tiles staged once/block into double-buffered swizzled LDS
// (2-phase pipeline).  Q pre-scaled by log2(e)/8 so P = exp2(s - m): native
// v_exp_f32, no per-element multiply.  Defer-max THR = 11.5 (log2 units).
// ---------------------------------------------------------------------------
__launch_bounds__(256)
__global__ void attn_mfma_k(const _Float16* __restrict__ Q,
                            const _Float16* __restrict__ K,
                            const _Float16* __restrict__ VT,
                            _Float16* __restrict__ O)
{
    __shared__ _Float16 Kls[2][64 * 64];   // [buf][k_row][d], swizzled rows
    __shared__ _Float16 Vls[2][64 * 64];   // [buf][d][k],     swizzled rows
    __shared__ _Float16 Pl[4 * 1024];      // 2KB per wave

    const int tid  = threadIdx.x;
    const int wv   = tid >> 6;
    const int lane = tid & 63;
    const int l15  = lane & 15;
    const int lg   = lane >> 4;

    const int bh = blockIdx.y;
    const int b  = bh / NH, h = bh - b * NH;
    const int q0 = blockIdx.x * 64 + wv * 16;

    const _Float16* Qb = Q + (size_t)bh * SS * DK;
    const char* Kb = (const char*)(K  + (size_t)bh * SS * DK);
    const char* Vb = (const char*)(VT + (size_t)bh * DK * SS);

#define ATTN_STAGE(buf, kt)                                                   \
    {                                                                         \
        _Pragma("unroll")                                                     \
        for (int w = 0; w < 4; w++) {                                         \
            int inst = wv + w * 4;                                            \
            bool isK = inst < 8;                                              \
            int li = isK ? inst : inst - 8;                                   \
            int p  = li * 1024 + lane * 16;                                   \
            int lo = p ^ (((p >> 7) & 7) << 4);                               \
            int row = lo >> 7, kbyte = lo & 127;                              \
            const char* src = isK                                             \
                ? (Kb + (size_t)((kt) + row) * 128 + kbyte)                   \
                : (Vb + (size_t)row * (SS * 2) + (size_t)(kt) * 2 + kbyte);   \
            char* dst = (isK ? (char*)Kls[buf] : (char*)Vls[buf]) + li * 1024;\
            __builtin_amdgcn_global_load_lds(                                 \
                (const __attribute__((address_space(1))) void*)src,           \
                (__attribute__((address_space(3))) void*)dst, 16, 0, 0);      \
        }                                                                     \
    }

    ATTN_STAGE(0, 0);

    // Q fragments, pre-scaled by log2(e)/sqrt(dk) = 1.44269504/8
    half8 qa0 = *(const half8*)&Qb[(size_t)(q0 + l15) * DK + lg * 8];
    half8 qa1 = *(const half8*)&Qb[(size_t)(q0 + l15) * DK + 32 + lg * 8];
    #pragma unroll
    for (int i = 0; i < 8; i++) {
        qa0[i] = qa0[i] * (_Float16)0.18033688f;
        qa1[i] = qa1[i] * (_Float16)0.18033688f;
    }

    f32x4 po[4];
    float m_[4], l_[4];
    #pragma unroll
    for (int r = 0; r < 4; r++) {
        po[r][0] = po[r][1] = po[r][2] = po[r][3] = 0.0f;
        m_[r] = -1e30f; l_[r] = 0.0f;
    }

    char* Pw = (char*)&Pl[wv * 1024];
    const int prd = (l15 * 128 + lg * 16) ^ ((l15 & 7) << 4);

    asm volatile("s_waitcnt vmcnt(0)" ::: "memory");
    __syncthreads();

    for (int it = 0; it < SS / 64; ++it) {
        const int cur = it & 1;
        if (it + 1 < SS / 64) ATTN_STAGE(cur ^ 1, (it + 1) * 64);

        const char* Kc = (const char*)Kls[cur];
        const char* Vc = (const char*)Vls[cur];

        // ---- S = (Q*log2e/8) K^T : scores in log2 units
        f32x4 sc[4];
        __builtin_amdgcn_s_setprio(1);
        #pragma unroll
        for (int t = 0; t < 4; t++) {
            int row = t * 16 + l15;
            int off0 = (row * 128 + lg * 16) ^ ((row & 7) << 4);
            int off1 = (row * 128 + 64 + lg * 16) ^ ((row & 7) << 4);
            half8 kb0 = *(const half8*)(Kc + off0);
            half8 kb1 = *(const half8*)(Kc + off1);
            f32x4 z;
            z[0] = z[1] = z[2] = z[3] = 0.0f;
            z = __builtin_amdgcn_mfma_f32_16x16x32_f16(qa0, kb0, z, 0, 0, 0);
            sc[t] = __builtin_amdgcn_mfma_f32_16x16x32_f16(qa1, kb1, z, 0, 0, 0);
        }
        __builtin_amdgcn_s_setprio(0);

        // ---- online softmax, log2 domain, defer-max (THR=11.5 ~ 8 nats)
        float rmv[4];
        float need = 0.0f;
        #pragma unroll
        for (int r = 0; r < 4; r++) {
            float rm = fmaxf(fmaxf(sc[0][r], sc[1][r]), fmaxf(sc[2][r], sc[3][r]));
            rm = fmaxf(rm, __shfl_xor(rm, 1));
            rm = fmaxf(rm, __shfl_xor(rm, 2));
            rm = fmaxf(rm, __shfl_xor(rm, 4));
            rm = fmaxf(rm, __shfl_xor(rm, 8));
            rmv[r] = rm;
            need = fmaxf(need, rm - m_[r]);
        }
        if (!__all(need <= 11.5f)) {
            #pragma unroll
            for (int r = 0; r < 4; r++) {
                float mn = fmaxf(m_[r], rmv[r]);
                float alpha = exp2f(m_[r] - mn);
                m_[r] = mn;
                l_[r] *= alpha;
                #pragma unroll
                for (int dt = 0; dt < 4; dt++) po[dt][r] *= alpha;
            }
        }
        #pragma unroll
        for (int r = 0; r < 4; r++) {
            float rs = 0.0f;
            #pragma unroll
            for (int t = 0; t < 4; t++) {
                float p = exp2f(sc[t][r] - m_[r]);
                sc[t][r] = p;
                rs += p;
            }
            rs += __shfl_xor(rs, 1);
            rs += __shfl_xor(rs, 2);
            rs += __shfl_xor(rs, 4);
            rs += __shfl_xor(rs, 8);
            l_[r] += rs;
        }

        // ---- P -> per-wave LDS (fp16, swizzled), intra-wave round-trip
        #pragma unroll
        for (int t = 0; t < 4; t++)
            #pragma unroll
            for (int r = 0; r < 4; r++) {
                int row = lg * 4 + r, col = t * 16 + l15;
                int off = (row * 128 + col * 2) ^ ((row & 7) << 4);
                *(_Float16*)(Pw + off) = (_Float16)sc[t][r];
            }
        asm volatile("s_waitcnt lgkmcnt(0)" ::: "memory");
        __builtin_amdgcn_sched_barrier(0);

        half8 pa0 = *(const half8*)(Pw + prd);
        half8 pa1 = *(const half8*)(Pw + (prd ^ 64));

        // ---- O += P @ V (V^T tile in LDS: row=d, col=k)
        __builtin_amdgcn_s_setprio(1);
        #pragma unroll
        for (int dt = 0; dt < 4; dt++) {
            int row = dt * 16 + l15;
            int off0 = (row * 128 + lg * 16) ^ ((row & 7) << 4);
            int off1 = (row * 128 + 64 + lg * 16) ^ ((row & 7) << 4);
            half8 vb0 = *(const half8*)(Vc + off0);
            half8 vb1 = *(const half8*)(Vc + off1);
            po[dt] = __builtin_amdgcn_mfma_f32_16x16x32_f16(pa0, vb0, po[dt], 0, 0, 0);
            po[dt] = __builtin_amdgcn_mfma_f32_16x16x32_f16(pa1, vb1, po[dt], 0, 0, 0);
        }
        __builtin_amdgcn_s_setprio(0);

        asm volatile("s_waitcnt vmcnt(0)" ::: "memory");
        __syncthreads();
    }
#undef ATTN_STAGE

    // ---- normalize, store fp16 [B,S,D]
    #pragma unroll
    for (int r = 0; r < 4; r++) {
        float inv = 1.0f / l_[r];
        int qrow = q0 + lg * 4 + r;
        size_t base = (size_t)(b * SS + qrow) * D_MODEL + h * DK;
        #pragma unroll
        for (int dt = 0; dt < 4; dt++)
            O[base + dt * 16 + l15] = (_Float16)(po[dt][r] * inv);
    }
}

// ---------------------------------------------------------------------------
// Fused residual-add + LayerNorm, wave-per-row (no LDS, no block barrier).
// 4 rows per 256-thread block.  RH: residual fp16.  OH: out fp16.
// ---------------------------------------------------------------------------
template<bool RH, bool OH>
__launch_bounds__(256)
__global__ void ln_k(const void* __restrict__ xres, const float* __restrict__ y,
                     const float* __restrict__ gamma, const float* __restrict__ beta,
                     void* __restrict__ outp)
{
    const int row  = blockIdx.x * 4 + (threadIdx.x >> 6);
    const int lane = threadIdx.x & 63;
    const size_t base = (size_t)row * D_MODEL;

    float v[12];
    float sum = 0.0f, ssq = 0.0f;
    #pragma unroll
    for (int ch = 0; ch < 3; ch++) {
        int col = ch * 256 + lane * 4;
        float4 yv = *(const float4*)&y[base + col];
        float xr[4];
        if (RH) {
            half4 hv = *(const half4*)((const _Float16*)xres + base + col);
            #pragma unroll
            for (int i = 0; i < 4; i++) xr[i] = (float)hv[i];
        } else {
            float4 xv = *(const float4*)((const float*)xres + base + col);
            xr[0] = xv.x; xr[1] = xv.y; xr[2] = xv.z; xr[3] = xv.w;
        }
        float yy[4] = {yv.x, yv.y, yv.z, yv.w};
        #pragma unroll
        for (int i = 0; i < 4; i++) {
            float t = xr[i] + yy[i];
            v[ch * 4 + i] = t;
            sum += t;
            ssq += t * t;
        }
    }
    #pragma unroll
    for (int msk = 32; msk >= 1; msk >>= 1) {
        sum += __shfl_xor(sum, msk);
        ssq += __shfl_xor(ssq, msk);
    }

    const float mu  = sum * (1.0f / D_MODEL);
    const float var = ssq * (1.0f / D_MODEL) - mu * mu;
    const float inv = rsqrtf(var + 1e-5f);

    #pragma unroll
    for (int ch = 0; ch < 3; ch++) {
        int col = ch * 256 + lane * 4;
        float4 gv = *(const float4*)&gamma[col];
        float4 bv = *(const float4*)&beta[col];
        float g[4] = {gv.x, gv.y, gv.z, gv.w};
        float be[4] = {bv.x, bv.y, bv.z, bv.w};
        if (OH) {
            half4 o;
            #pragma unroll
            for (int i = 0; i < 4; i++)
                o[i] = (_Float16)((v[ch * 4 + i] - mu) * inv * g[i] + be[i]);
            *(half4*)((_Float16*)outp + base + col) = o;
        } else {
            float4 o;
            o.x = (v[ch * 4 + 0] - mu) * inv * g[0] + be[0];
            o.y = (v[ch * 4 + 1] - mu) * inv * g[1] + be[1];
            o.z = (v[ch * 4 + 2] - mu) * inv * g[2] + be[2];
            o.w = (v[ch * 4 + 3] - mu) * inv * g[3] + be[3];
            *(float4*)((float*)outp + base + col) = o;
        }
    }
}

// ---------------------------------------------------------------------------
// casts: x fp32 -> fp16 (vectorized), weight fp32 [K][N] -> fp16 [N][K]
// ---------------------------------------------------------------------------
__launch_bounds__(256)
__global__ void castx_k(const float* __restrict__ in, _Float16* __restrict__ out,
                        int n8)
{
    int i = blockIdx.x * 256 + threadIdx.x;
    if (i < n8) {
        float4 a = ((const float4*)in)[2 * i];
        float4 b = ((const float4*)in)[2 * i + 1];
        half8 h = {(_Float16)a.x, (_Float16)a.y, (_Float16)a.z, (_Float16)a.w,
                   (_Float16)b.x, (_Float16)b.y, (_Float16)b.z, (_Float16)b.w};
        ((half8*)out)[i] = h;
    }
}

__launch_bounds__(256)
__global__ void wcast_k(const float* __restrict__ src, _Float16* __restrict__ dst,
                        int K, int N)
{
    __shared__ float t[32][33];
    const int k0 = blockIdx.y * 32, n0 = blockIdx.x * 32;
    const int c = threadIdx.x & 31, r8 = threadIdx.x >> 5;
    #pragma unroll
    for (int rr = 0; rr < 4; rr++) {
        int r = rr * 8 + r8;
        t[r][c] = src[(size_t)(k0 + r) * N + n0 + c];
    }
    __syncthreads();
    #pragma unroll
    for (int rr = 0; rr < 4; rr++) {
        int n = rr * 8 + r8;
        dst[(size_t)(n0 + n) * K + k0 + c] = (_Float16)t[c][n];
    }
}

// ---------------------------------------------------------------------------
extern "C" void kernel_launch(void* const* d_in, const int* in_sizes, int n_in,
                              void* d_out, int out_size, void* d_ws, size_t ws_size,
                              hipStream_t stream)
{
    const float* x     = (const float*)d_in[0];
    const float* w_qkv = (const float*)d_in[1];
    const float* b_qkv = (const float*)d_in[2];
    const float* w_out = (const float*)d_in[3];
    const float* b_out = (const float*)d_in[4];
    const float* w1    = (const float*)d_in[5];
    const float* b1    = (const float*)d_in[6];
    const float* w2    = (const float*)d_in[7];
    const float* b2    = (const float*)d_in[8];
    const float* g1    = (const float*)d_in[9];
    const float* be1   = (const float*)d_in[10];
    const float* g2    = (const float*)d_in[11];
    const float* be2   = (const float*)d_in[12];

    char* w = (char*)d_ws;
    // byte layout (total ~64.5 MB):
    //  [0,6.29M)   q fp16            \
    //  [6.29,12.58M) k fp16           > later overlaid by ffn_h fp16 [0,25.17M)
    //  [12.58,18.87M) vT fp16        /
    //  [25.17,31.46M) xh fp16 -> attn_oh fp16 (sequential lifetimes)
    //  [31.46,35.00M) wqkvT | [35.00,36.18M) woutT
    //  [36.18,40.90M) w1T   | [40.90,45.62M) w2T
    //  [45.62,58.20M) attn_proj fp32 -> ffn_out fp32 (sequential lifetimes)
    //  [58.20,64.49M) x1h fp16
    _Float16* q        = (_Float16*)(w);
    _Float16* kk       = (_Float16*)(w + 6291456);
    _Float16* vv       = (_Float16*)(w + 12582912);
    _Float16* ffn_h    = (_Float16*)(w);
    _Float16* xh       = (_Float16*)(w + 25165824);
    _Float16* attn_oh  = (_Float16*)(w + 25165824);
    _Float16* wqkvT    = (_Float16*)(w + 31457280);
    _Float16* woutT    = (_Float16*)(w + 34996224);
    _Float16* w1T      = (_Float16*)(w + 36175872);
    _Float16* w2T      = (_Float16*)(w + 40894464);
    float*    attn_proj= (float*)(w + 45613056);
    float*    ffn_out  = (float*)(w + 45613056);
    _Float16* x1h      = (_Float16*)(w + 58195968);
    float* out = (float*)d_out;

    dim3 blk(256);

    // 0) casts: x -> fp16; weights -> fp16 transposed [N][K]
    castx_k<<<(MM * D_MODEL / 8 + 255) / 256, blk, 0, stream>>>(x, xh, MM * D_MODEL / 8);
    wcast_k<<<dim3(2304 / 32, 768 / 32), blk, 0, stream>>>(w_qkv, wqkvT, 768, 2304);
    wcast_k<<<dim3(768 / 32, 768 / 32), blk, 0, stream>>>(w_out, woutT, 768, 768);
    wcast_k<<<dim3(3072 / 32, 768 / 32), blk, 0, stream>>>(w1, w1T, 768, 3072);
    wcast_k<<<dim3(768 / 32, 3072 / 32), blk, 0, stream>>>(w2, w2T, 3072, 768);

    // 1) QKV: xh @ w_qkv + b -> q/k [B,H,S,dk], v^T [B,H,dk,S], all fp16
    hgemm_k<4, 2><<<dim3(2304 / 128, MM / 128), blk, 0, stream>>>(
        xh, wqkvT, b_qkv, nullptr, nullptr, MM, 2304, D_MODEL, q, kk, vv);

    // 2) flash attention -> attn_oh fp16 [B,S,D]
    attn_mfma_k<<<dim3(SS / 64, BB * NH), blk, 0, stream>>>(q, kk, vv, attn_oh);

    // 3) out projection -> attn_proj fp32
    hgemm_k<2, 0><<<dim3(768 / 128, MM / 64), blk, 0, stream>>>(
        attn_oh, woutT, b_out, attn_proj, nullptr, MM, D_MODEL, D_MODEL,
        nullptr, nullptr, nullptr);

    // 4) x1h = fp16( LN(x + attn_proj) )
    ln_k<false, true><<<MM / 4, blk, 0, stream>>>(x, attn_proj, g1, be1, x1h);

    // 5) ffn_h = fp16( gelu(x1 @ w1 + b1) )
    hgemm_k<4, 1><<<dim3(DFF / 128, MM / 128), blk, 0, stream>>>(
        x1h, w1T, b1, nullptr, ffn_h, MM, DFF, D_MODEL, nullptr, nullptr, nullptr);

    // 6) ffn_out = ffn_h @ w2 + b2 (fp32)
    hgemm_k<2, 0><<<dim3(768 / 128, MM / 64), blk, 0, stream>>>(
        ffn_h, w2T, b2, ffn_out, nullptr, MM, D_MODEL, DFF, nullptr, nullptr, nullptr);

    // 7) out = LN(x1 + ffn_out) fp32
    ln_k<true, false><<<MM / 4, blk, 0, stream>>>(x1h, ffn_out, g2, be2, out);
}

// Round 11
// 325.449 us; speedup vs baseline: 1.0821x; 1.0821x over previous
//
#include <hip/hip_runtime.h>
#include <hip/hip_bf16.h>
#include <math.h>

#define D_MODEL 768
#define NH 12
#define DFF 3072
#define BB 2
#define SS 2048
#define MM (BB*SS)   /* 4096 rows total */
#define DK 64

typedef _Float16 half8 __attribute__((ext_vector_type(8)));
typedef _Float16 half4 __attribute__((ext_vector_type(4)));
typedef float f32x4 __attribute__((ext_vector_type(4)));

// ---------------------------------------------------------------------------
// fp16 MFMA GEMM, 2-PHASE PIPELINED: C[M,N] = A[M,K] @ W[K,N] + bias.
// A fp16 row-major, W TRANSPOSED fp16 (Bt[N][K]).  Tiles: BM x 128, BK=64.
// 4 waves (2x2), wave tile (AM*16) x 64, mfma_f32_16x16x32_f16.
// EPI: 0 = bias, fp32 C | 1 = bias+tanh-GELU, fp16 C | 2 = bias, QKV scatter
// ---------------------------------------------------------------------------
template<int AM, int EPI>
__launch_bounds__(256)
__global__ void hgemm_k(const _Float16* __restrict__ A,
                        const _Float16* __restrict__ Bt,
                        const float* __restrict__ bias,
                        float* __restrict__ Cf, _Float16* __restrict__ Ch,
                        int M, int N, int K,
                        _Float16* __restrict__ qo, _Float16* __restrict__ ko,
                        _Float16* __restrict__ vo)
{
    constexpr int BM = AM * 32;        // 128 or 64
    constexpr int NA = BM / 8;         // A-stage instructions (1024B each)
    constexpr int NI = NA + 16;        // total stage instrs per K-step
    __shared__ _Float16 Als[2][BM * 64];   // [buf][BM][64] fp16, swizzled
    __shared__ _Float16 Bls[2][128 * 64];  // [buf][128][64]

    const int tid  = threadIdx.x;
    const int wv   = tid >> 6, lane = tid & 63;
    const int l15  = lane & 15, lg = lane >> 4;
    const int wr   = wv >> 1,  wc = wv & 1;
    const int m0   = blockIdx.y * BM, n0 = blockIdx.x * 128;

    f32x4 acc[AM][4];
    #pragma unroll
    for (int m = 0; m < AM; m++)
        #pragma unroll
        for (int n = 0; n < 4; n++)
            acc[m][n][0] = acc[m][n][1] = acc[m][n][2] = acc[m][n][3] = 0.0f;

    const char* Ab = (const char*)A;
    const char* Bb = (const char*)Bt;

    // stage K-tile kt into buffer buf: linear dest, inverse-swizzled source
#define GSTAGE(buf, kt)                                                       \
    {                                                                         \
        _Pragma("unroll")                                                     \
        for (int inst = wv; inst < NI; inst += 4) {                           \
            const bool isA = inst < NA;                                       \
            const int  li  = isA ? inst : inst - NA;                          \
            const int  p   = li * 1024 + lane * 16;                           \
            const int  lo  = p ^ (((p >> 7) & 7) << 4);                       \
            const int  row = lo >> 7, kb = lo & 127;                          \
            const char* src = isA                                             \
                ? Ab + ((size_t)(m0 + row) * K + (kt)) * 2 + kb               \
                : Bb + ((size_t)(n0 + row) * K + (kt)) * 2 + kb;              \
            char* dst = (isA ? (char*)Als[buf] : (char*)Bls[buf]) + li * 1024;\
            __builtin_amdgcn_global_load_lds(                                 \
                (const __attribute__((address_space(1))) void*)src,           \
                (__attribute__((address_space(3))) void*)dst, 16, 0, 0);      \
        }                                                                     \
    }

    GSTAGE(0, 0);
    asm volatile("s_waitcnt vmcnt(0)" ::: "memory");
    __syncthreads();

    const int nt = K >> 6;
    for (int it = 0; it < nt; ++it) {
        const int cur = it & 1;
        if (it + 1 < nt) GSTAGE(cur ^ 1, (it + 1) << 6);

        const char* Al = (const char*)Als[cur];
        const char* Bl = (const char*)Bls[cur];

        __builtin_amdgcn_s_setprio(1);
        #pragma unroll
        for (int ks = 0; ks < 2; ks++) {
            half8 af[AM], bf[4];
            #pragma unroll
            for (int m = 0; m < AM; m++) {
                int row = wr * (AM * 16) + m * 16 + l15;
                int off = (row * 128 + ks * 64 + lg * 16) ^ ((row & 7) << 4);
                af[m] = *(const half8*)(Al + off);
            }
            #pragma unroll
            for (int n = 0; n < 4; n++) {
                int row = wc * 64 + n * 16 + l15;
                int off = (row * 128 + ks * 64 + lg * 16) ^ ((row & 7) << 4);
                bf[n] = *(const half8*)(Bl + off);
            }
            #pragma unroll
            for (int m = 0; m < AM; m++)
                #pragma unroll
                for (int n = 0; n < 4; n++)
                    acc[m][n] = __builtin_amdgcn_mfma_f32_16x16x32_f16(
                        af[m], bf[n], acc[m][n], 0, 0, 0);
        }
        __builtin_amdgcn_s_setprio(0);

        asm volatile("s_waitcnt vmcnt(0)" ::: "memory");
        __syncthreads();
    }
#undef GSTAGE

    // ---- epilogue.  C/D: col=l15, row=lg*4+r
    #pragma unroll
    for (int m = 0; m < AM; m++) {
        #pragma unroll
        for (int n = 0; n < 4; n++) {
            int col = n0 + wc * 64 + n * 16 + l15;
            float bs = bias[col];
            #pragma unroll
            for (int r = 0; r < 4; r++) {
                int row = m0 + wr * (AM * 16) + m * 16 + lg * 4 + r;
                float val = acc[m][n][r] + bs;
                if (EPI == 0) {
                    Cf[(size_t)row * N + col] = val;
                } else if (EPI == 1) {
                    // tanh-approx GELU (max err < 1e-3 vs erf form):
                    // u = x(1 + 0.044715 x^2); t = e^{1.5957691 u};
                    // gelu = 0.5 x (1 + (t-1)/(t+1))
                    float xx = val;
                    float u = xx * fmaf(0.044715f * xx, xx, 1.0f);
                    u = fminf(fmaxf(u, -9.0f), 9.0f);     // tanh saturated
                    float t = __expf(1.5957691f * u);
                    float th = (t - 1.0f) * __builtin_amdgcn_rcpf(t + 1.0f);
                    val = 0.5f * xx * (1.0f + th);
                    Ch[(size_t)row * N + col] = (_Float16)val;
                } else {
                    int which = col / D_MODEL;
                    int c = col - which * D_MODEL;
                    int hh = c >> 6, dd = c & 63;
                    int bq = row >> 11, si = row & 2047;
                    _Float16 hv = (_Float16)val;
                    if (which == 0)
                        qo[((((size_t)bq * NH + hh) * SS) + si) * DK + dd] = hv;
                    else if (which == 1)
                        ko[((((size_t)bq * NH + hh) * SS) + si) * DK + dd] = hv;
                    else
                        vo[(((size_t)bq * NH + hh) * DK + dd) * SS + si] = hv;
                }
            }
        }
    }
}

// ---------------------------------------------------------------------------
// MFMA flash attention v3: fp16 in / fp32 accum.
// Round-7 softmax (Q pre-scaled 1/8 exact, __expf, defer-max THR=8 nats)
// + row-sum l via P @ ones MFMA (removes 16 DPP-adds + 12 adds per tile).
// K/V^T staged once/block into double-buffered swizzled LDS, 2-phase.
// ---------------------------------------------------------------------------
__launch_bounds__(256)
__global__ void attn_mfma_k(const _Float16* __restrict__ Q,
                            const _Float16* __restrict__ K,
                            const _Float16* __restrict__ VT,
                            _Float16* __restrict__ O)
{
    __shared__ _Float16 Kls[2][64 * 64];   // [buf][k_row][d], swizzled rows
    __shared__ _Float16 Vls[2][64 * 64];   // [buf][d][k],     swizzled rows
    __shared__ _Float16 Pl[4 * 1024];      // 2KB per wave

    const int tid  = threadIdx.x;
    const int wv   = tid >> 6;
    const int lane = tid & 63;
    const int l15  = lane & 15;
    const int lg   = lane >> 4;

    const int bh = blockIdx.y;
    const int b  = bh / NH, h = bh - b * NH;
    const int q0 = blockIdx.x * 64 + wv * 16;

    const _Float16* Qb = Q + (size_t)bh * SS * DK;
    const char* Kb = (const char*)(K  + (size_t)bh * SS * DK);
    const char* Vb = (const char*)(VT + (size_t)bh * DK * SS);

#define ATTN_STAGE(buf, kt)                                                   \
    {                                                                         \
        _Pragma("unroll")                                                     \
        for (int w = 0; w < 4; w++) {                                         \
            int inst = wv + w * 4;                                            \
            bool isK = inst < 8;                                              \
            int li = isK ? inst : inst - 8;                                   \
            int p  = li * 1024 + lane * 16;                                   \
            int lo = p ^ (((p >> 7) & 7) << 4);                               \
            int row = lo >> 7, kbyte = lo & 127;                              \
            const char* src = isK                                             \
                ? (Kb + (size_t)((kt) + row) * 128 + kbyte)                   \
                : (Vb + (size_t)row * (SS * 2) + (size_t)(kt) * 2 + kbyte);   \
            char* dst = (isK ? (char*)Kls[buf] : (char*)Vls[buf]) + li * 1024;\
            __builtin_amdgcn_global_load_lds(                                 \
                (const __attribute__((address_space(1))) void*)src,           \
                (__attribute__((address_space(3))) void*)dst, 16, 0, 0);      \
        }                                                                     \
    }

    ATTN_STAGE(0, 0);

    // Q fragments, pre-scaled by 1/sqrt(dk)=1/8 (exact in fp16)
    half8 qa0 = *(const half8*)&Qb[(size_t)(q0 + l15) * DK + lg * 8];
    half8 qa1 = *(const half8*)&Qb[(size_t)(q0 + l15) * DK + 32 + lg * 8];
    #pragma unroll
    for (int i = 0; i < 8; i++) {
        qa0[i] = qa0[i] * (_Float16)0.125f;
        qa1[i] = qa1[i] * (_Float16)0.125f;
    }

    const half8 ones = {(_Float16)1.0f, (_Float16)1.0f, (_Float16)1.0f,
                        (_Float16)1.0f, (_Float16)1.0f, (_Float16)1.0f,
                        (_Float16)1.0f, (_Float16)1.0f};

    f32x4 po[4];
    float m_[4], l_[4];
    #pragma unroll
    for (int r = 0; r < 4; r++) {
        po[r][0] = po[r][1] = po[r][2] = po[r][3] = 0.0f;
        m_[r] = -1e30f; l_[r] = 0.0f;
    }

    char* Pw = (char*)&Pl[wv * 1024];
    const int prd = (l15 * 128 + lg * 16) ^ ((l15 & 7) << 4);

    asm volatile("s_waitcnt vmcnt(0)" ::: "memory");
    __syncthreads();

    for (int it = 0; it < SS / 64; ++it) {
        const int cur = it & 1;
        if (it + 1 < SS / 64) ATTN_STAGE(cur ^ 1, (it + 1) * 64);

        const char* Kc = (const char*)Kls[cur];
        const char* Vc = (const char*)Vls[cur];

        // ---- S = (Q/8) K^T : 4 tiles of 16x16, 2 MFMAs each
        f32x4 sc[4];
        __builtin_amdgcn_s_setprio(1);
        #pragma unroll
        for (int t = 0; t < 4; t++) {
            int row = t * 16 + l15;
            int off0 = (row * 128 + lg * 16) ^ ((row & 7) << 4);
            int off1 = (row * 128 + 64 + lg * 16) ^ ((row & 7) << 4);
            half8 kb0 = *(const half8*)(Kc + off0);
            half8 kb1 = *(const half8*)(Kc + off1);
            f32x4 z;
            z[0] = z[1] = z[2] = z[3] = 0.0f;
            z = __builtin_amdgcn_mfma_f32_16x16x32_f16(qa0, kb0, z, 0, 0, 0);
            sc[t] = __builtin_amdgcn_mfma_f32_16x16x32_f16(qa1, kb1, z, 0, 0, 0);
        }
        __builtin_amdgcn_s_setprio(0);

        // ---- online softmax with defer-max (THR=8 nats); l via MFMA below
        float rmv[4];
        float need = 0.0f;
        #pragma unroll
        for (int r = 0; r < 4; r++) {
            float rm = fmaxf(fmaxf(sc[0][r], sc[1][r]), fmaxf(sc[2][r], sc[3][r]));
            rm = fmaxf(rm, __shfl_xor(rm, 1));
            rm = fmaxf(rm, __shfl_xor(rm, 2));
            rm = fmaxf(rm, __shfl_xor(rm, 4));
            rm = fmaxf(rm, __shfl_xor(rm, 8));
            rmv[r] = rm;
            need = fmaxf(need, rm - m_[r]);
        }
        if (!__all(need <= 8.0f)) {
            #pragma unroll
            for (int r = 0; r < 4; r++) {
                float mn = fmaxf(m_[r], rmv[r]);
                float alpha = __expf(m_[r] - mn);
                m_[r] = mn;
                l_[r] *= alpha;
                #pragma unroll
                for (int dt = 0; dt < 4; dt++) po[dt][r] *= alpha;
            }
        }
        #pragma unroll
        for (int r = 0; r < 4; r++)
            #pragma unroll
            for (int t = 0; t < 4; t++)
                sc[t][r] = __expf(sc[t][r] - m_[r]);

        // ---- P -> per-wave LDS (fp16, swizzled), intra-wave round-trip
        #pragma unroll
        for (int t = 0; t < 4; t++)
            #pragma unroll
            for (int r = 0; r < 4; r++) {
                int row = lg * 4 + r, col = t * 16 + l15;
                int off = (row * 128 + col * 2) ^ ((row & 7) << 4);
                *(_Float16*)(Pw + off) = (_Float16)sc[t][r];
            }
        asm volatile("s_waitcnt lgkmcnt(0)" ::: "memory");
        __builtin_amdgcn_sched_barrier(0);

        half8 pa0 = *(const half8*)(Pw + prd);
        half8 pa1 = *(const half8*)(Pw + (prd ^ 64));

        __builtin_amdgcn_s_setprio(1);
        // ---- l += P @ ones  (row-sum via matrix pipe; every col = sum_k P)
        {
            f32x4 lz;
            lz[0] = lz[1] = lz[2] = lz[3] = 0.0f;
            lz = __builtin_amdgcn_mfma_f32_16x16x32_f16(pa0, ones, lz, 0, 0, 0);
            lz = __builtin_amdgcn_mfma_f32_16x16x32_f16(pa1, ones, lz, 0, 0, 0);
            #pragma unroll
            for (int r = 0; r < 4; r++) l_[r] += lz[r];
        }

        // ---- O += P @ V (V^T tile in LDS: row=d, col=k)
        #pragma unroll
        for (int dt = 0; dt < 4; dt++) {
            int row = dt * 16 + l15;
            int off0 = (row * 128 + lg * 16) ^ ((row & 7) << 4);
            int off1 = (row * 128 + 64 + lg * 16) ^ ((row & 7) << 4);
            half8 vb0 = *(const half8*)(Vc + off0);
            half8 vb1 = *(const half8*)(Vc + off1);
            po[dt] = __builtin_amdgcn_mfma_f32_16x16x32_f16(pa0, vb0, po[dt], 0, 0, 0);
            po[dt] = __builtin_amdgcn_mfma_f32_16x16x32_f16(pa1, vb1, po[dt], 0, 0, 0);
        }
        __builtin_amdgcn_s_setprio(0);

        asm volatile("s_waitcnt vmcnt(0)" ::: "memory");
        __syncthreads();
    }
#undef ATTN_STAGE

    // ---- normalize, store fp16 [B,S,D]
    #pragma unroll
    for (int r = 0; r < 4; r++) {
        float inv = 1.0f / l_[r];
        int qrow = q0 + lg * 4 + r;
        size_t base = (size_t)(b * SS + qrow) * D_MODEL + h * DK;
        #pragma unroll
        for (int dt = 0; dt < 4; dt++)
            O[base + dt * 16 + l15] = (_Float16)(po[dt][r] * inv);
    }
}

// ---------------------------------------------------------------------------
// Fused residual-add + LayerNorm, wave-per-row (no LDS, no block barrier).
// 4 rows per 256-thread block.  RH: residual fp16.  OH: out fp16.
// ---------------------------------------------------------------------------
template<bool RH, bool OH>
__launch_bounds__(256)
__global__ void ln_k(const void* __restrict__ xres, const float* __restrict__ y,
                     const float* __restrict__ gamma, const float* __restrict__ beta,
                     void* __restrict__ outp)
{
    const int row  = blockIdx.x * 4 + (threadIdx.x >> 6);
    const int lane = threadIdx.x & 63;
    const size_t base = (size_t)row * D_MODEL;

    float v[12];
    float sum = 0.0f, ssq = 0.0f;
    #pragma unroll
    for (int ch = 0; ch < 3; ch++) {
        int col = ch * 256 + lane * 4;
        float4 yv = *(const float4*)&y[base + col];
        float xr[4];
        if (RH) {
            half4 hv = *(const half4*)((const _Float16*)xres + base + col);
            #pragma unroll
            for (int i = 0; i < 4; i++) xr[i] = (float)hv[i];
        } else {
            float4 xv = *(const float4*)((const float*)xres + base + col);
            xr[0] = xv.x; xr[1] = xv.y; xr[2] = xv.z; xr[3] = xv.w;
        }
        float yy[4] = {yv.x, yv.y, yv.z, yv.w};
        #pragma unroll
        for (int i = 0; i < 4; i++) {
            float t = xr[i] + yy[i];
            v[ch * 4 + i] = t;
            sum += t;
            ssq += t * t;
        }
    }
    #pragma unroll
    for (int msk = 32; msk >= 1; msk >>= 1) {
        sum += __shfl_xor(sum, msk);
        ssq += __shfl_xor(ssq, msk);
    }

    const float mu  = sum * (1.0f / D_MODEL);
    const float var = ssq * (1.0f / D_MODEL) - mu * mu;
    const float inv = rsqrtf(var + 1e-5f);

    #pragma unroll
    for (int ch = 0; ch < 3; ch++) {
        int col = ch * 256 + lane * 4;
        float4 gv = *(const float4*)&gamma[col];
        float4 bv = *(const float4*)&beta[col];
        float g[4] = {gv.x, gv.y, gv.z, gv.w};
        float be[4] = {bv.x, bv.y, bv.z, bv.w};
        if (OH) {
            half4 o;
            #pragma unroll
            for (int i = 0; i < 4; i++)
                o[i] = (_Float16)((v[ch * 4 + i] - mu) * inv * g[i] + be[i]);
            *(half4*)((_Float16*)outp + base + col) = o;
        } else {
            float4 o;
            o.x = (v[ch * 4 + 0] - mu) * inv * g[0] + be[0];
            o.y = (v[ch * 4 + 1] - mu) * inv * g[1] + be[1];
            o.z = (v[ch * 4 + 2] - mu) * inv * g[2] + be[2];
            o.w = (v[ch * 4 + 3] - mu) * inv * g[3] + be[3];
            *(float4*)((float*)outp + base + col) = o;
        }
    }
}

// ---------------------------------------------------------------------------
// casts: x fp32 -> fp16 (vectorized), weight fp32 [K][N] -> fp16 [N][K]
// ---------------------------------------------------------------------------
__launch_bounds__(256)
__global__ void castx_k(const float* __restrict__ in, _Float16* __restrict__ out,
                        int n8)
{
    int i = blockIdx.x * 256 + threadIdx.x;
    if (i < n8) {
        float4 a = ((const float4*)in)[2 * i];
        float4 b = ((const float4*)in)[2 * i + 1];
        half8 h = {(_Float16)a.x, (_Float16)a.y, (_Float16)a.z, (_Float16)a.w,
                   (_Float16)b.x, (_Float16)b.y, (_Float16)b.z, (_Float16)b.w};
        ((half8*)out)[i] = h;
    }
}

__launch_bounds__(256)
__global__ void wcast_k(const float* __restrict__ src, _Float16* __restrict__ dst,
                        int K, int N)
{
    __shared__ float t[32][33];
    const int k0 = blockIdx.y * 32, n0 = blockIdx.x * 32;
    const int c = threadIdx.x & 31, r8 = threadIdx.x >> 5;
    #pragma unroll
    for (int rr = 0; rr < 4; rr++) {
        int r = rr * 8 + r8;
        t[r][c] = src[(size_t)(k0 + r) * N + n0 + c];
    }
    __syncthreads();
    #pragma unroll
    for (int rr = 0; rr < 4; rr++) {
        int n = rr * 8 + r8;
        dst[(size_t)(n0 + n) * K + k0 + c] = (_Float16)t[c][n];
    }
}

// ---------------------------------------------------------------------------
extern "C" void kernel_launch(void* const* d_in, const int* in_sizes, int n_in,
                              void* d_out, int out_size, void* d_ws, size_t ws_size,
                              hipStream_t stream)
{
    const float* x     = (const float*)d_in[0];
    const float* w_qkv = (const float*)d_in[1];
    const float* b_qkv = (const float*)d_in[2];
    const float* w_out = (const float*)d_in[3];
    const float* b_out = (const float*)d_in[4];
    const float* w1    = (const float*)d_in[5];
    const float* b1    = (const float*)d_in[6];
    const float* w2    = (const float*)d_in[7];
    const float* b2    = (const float*)d_in[8];
    const float* g1    = (const float*)d_in[9];
    const float* be1   = (const float*)d_in[10];
    const float* g2    = (const float*)d_in[11];
    const float* be2   = (const float*)d_in[12];

    char* w = (char*)d_ws;
    _Float16* q        = (_Float16*)(w);
    _Float16* kk       = (_Float16*)(w + 6291456);
    _Float16* vv       = (_Float16*)(w + 12582912);
    _Float16* ffn_h    = (_Float16*)(w);
    _Float16* xh       = (_Float16*)(w + 25165824);
    _Float16* attn_oh  = (_Float16*)(w + 25165824);
    _Float16* wqkvT    = (_Float16*)(w + 31457280);
    _Float16* woutT    = (_Float16*)(w + 34996224);
    _Float16* w1T      = (_Float16*)(w + 36175872);
    _Float16* w2T      = (_Float16*)(w + 40894464);
    float*    attn_proj= (float*)(w + 45613056);
    float*    ffn_out  = (float*)(w + 45613056);
    _Float16* x1h      = (_Float16*)(w + 58195968);
    float* out = (float*)d_out;

    dim3 blk(256);

    // 0) casts: x -> fp16; weights -> fp16 transposed [N][K]
    castx_k<<<(MM * D_MODEL / 8 + 255) / 256, blk, 0, stream>>>(x, xh, MM * D_MODEL / 8);
    wcast_k<<<dim3(2304 / 32, 768 / 32), blk, 0, stream>>>(w_qkv, wqkvT, 768, 2304);
    wcast_k<<<dim3(768 / 32, 768 / 32), blk, 0, stream>>>(w_out, woutT, 768, 768);
    wcast_k<<<dim3(3072 / 32, 768 / 32), blk, 0, stream>>>(w1, w1T, 768, 3072);
    wcast_k<<<dim3(768 / 32, 3072 / 32), blk, 0, stream>>>(w2, w2T, 3072, 768);

    // 1) QKV: xh @ w_qkv + b -> q/k [B,H,S,dk], v^T [B,H,dk,S], all fp16
    hgemm_k<4, 2><<<dim3(2304 / 128, MM / 128), blk, 0, stream>>>(
        xh, wqkvT, b_qkv, nullptr, nullptr, MM, 2304, D_MODEL, q, kk, vv);

    // 2) flash attention -> attn_oh fp16 [B,S,D]
    attn_mfma_k<<<dim3(SS / 64, BB * NH), blk, 0, stream>>>(q, kk, vv, attn_oh);

    // 3) out projection -> attn_proj fp32
    hgemm_k<2, 0><<<dim3(768 / 128, MM / 64), blk, 0, stream>>>(
        attn_oh, woutT, b_out, attn_proj, nullptr, MM, D_MODEL, D_MODEL,
        nullptr, nullptr, nullptr);

    // 4) x1h = fp16( LN(x + attn_proj) )
    ln_k<false, true><<<MM / 4, blk, 0, stream>>>(x, attn_proj, g1, be1, x1h);

    // 5) ffn_h = fp16( gelu(x1 @ w1 + b1) )
    hgemm_k<4, 1><<<dim3(DFF / 128, MM / 128), blk, 0, stream>>>(
        x1h, w1T, b1, nullptr, ffn_h, MM, DFF, D_MODEL, nullptr, nullptr, nullptr);

    // 6) ffn_out = ffn_h @ w2 + b2 (fp32)
    hgemm_k<2, 0><<<dim3(768 / 128, MM / 64), blk, 0, stream>>>(
        ffn_h, w2T, b2, ffn_out, nullptr, MM, D_MODEL, DFF, nullptr, nullptr, nullptr);

    // 7) out = LN(x1 + ffn_out) fp32
    ln_k<true, false><<<MM / 4, blk, 0, stream>>>(x1h, ffn_out, g2, be2, out);
}